// Round 8
// baseline (474.890 us; speedup 1.0000x reference)
//
#include <hip/hip_runtime.h>
#include <cstdint>

// ---------------------------------------------------------------------------
// TransformerEncoderBlock: LN1 -> QKV -> MHA -> proj+res -> LN2 -> FC1+GELU
//                          -> FC2+res.  bf16 MFMA compute, fp32 accum.
// R13: revert to harness-proven templates + pipeline attn.
//   - gemm8 = R9's EXACT passed kernel (reads pre-barrier, gates P3/P7,
//     drain-free counted vmcnt, XCD swizzle). Used for QKV + FC1.
//   - gemm4 = R10's EXACT passed kernel (128^2, 2 blocks/CU, counted vmcnt).
//     Used for proj + FC2 (full 512-WG grid at N=1024).
//   - attn: replaced per-iter {global_load_lds; __syncthreads (vmcnt(0)
//     drain!)} with the PROVEN gemm4 ledger: double-buffered K/V, exactly
//     4 loads/wave/iter, per iter {compute buf[cur]; lgkmcnt(0); barrier;
//     stage kt+2 -> buf[cur]; vmcnt(4); barrier}. Prologue: stage Q(2) +
//     buf0(4) + buf1(4) = 10 outstanding; vmcnt(4) drains Q+buf0 (FIFO),
//     barrier -> collective. Induction identical to gemm4's (harness-proven).
//     Q-LDS aliased with Ps: both touch only wave-private rows (wave stages
//     and reads rows wave*16..+15 only); aq ds_reads are waited before the
//     first MFMA (compiler) which precedes the first Ps write in program
//     order; per-wave LDS ops complete in order. 40KB LDS -> 4 blocks/CU.
//   R11/R12's split-gate 8-phase ledger abandoned: 2 rounds failed with
//   un-isolatable race; sync-structure edits need HW race-screens (m152).
// ---------------------------------------------------------------------------

typedef unsigned short u16;
typedef short short8 __attribute__((ext_vector_type(8)));   // 8 bf16 = 4 VGPRs
typedef float floatx4 __attribute__((ext_vector_type(4)));  // MFMA C/D

#define GLB(p) ((const __attribute__((address_space(1))) void*)(p))
#define LDSP(p) ((__attribute__((address_space(3))) void*)(p))

__device__ __forceinline__ u16 f2bf(float f) {
    uint32_t u = __float_as_uint(f);
    u += 0x7fffu + ((u >> 16) & 1u);   // round-to-nearest-even
    return (u16)(u >> 16);
}
__device__ __forceinline__ uint32_t pack2(float a, float b) {
    return (uint32_t)f2bf(a) | ((uint32_t)f2bf(b) << 16);
}
__device__ __forceinline__ float fast_gelu(float v) {
    // 0.5*v*(1+tanh(0.79788456*(v+0.044715 v^3))), tanh via exp+rcp, branchless
    float u = v * (0.7978845608f + 0.0356774081f * v * v);
    float e = __expf(2.0f * u);                       // v_exp_f32
    float th = 1.0f - 2.0f * __builtin_amdgcn_rcpf(e + 1.0f); // v_rcp_f32
    return 0.5f * v * (1.0f + th);
}

// ---------------- transpose + cast: W[K,N] f32 -> Wt[N,K] bf16 --------------
__global__ __launch_bounds__(256) void transpose_cast_kernel(
    const float* __restrict__ W, u16* __restrict__ Wt, int K, int N)
{
    __shared__ float tile[32][33];
    int n0 = blockIdx.x * 32, k0 = blockIdx.y * 32;
    int tx = threadIdx.x, ty = threadIdx.y; // block (32,8)
    #pragma unroll
    for (int i = 0; i < 4; ++i)
        tile[ty + i * 8][tx] = W[(size_t)(k0 + ty + i * 8) * N + n0 + tx];
    __syncthreads();
    #pragma unroll
    for (int i = 0; i < 4; ++i)
        Wt[(size_t)(n0 + ty + i * 8) * K + k0 + tx] = f2bf(tile[tx][ty + i * 8]);
}

// ---------------- LayerNorm: fp32 [rows,1024] -> bf16 ----------------------
__global__ __launch_bounds__(256) void ln_kernel(
    const float* __restrict__ x, const float* __restrict__ gw,
    const float* __restrict__ bw, u16* __restrict__ out)
{
    const int row = blockIdx.x, tid = threadIdx.x;
    float4 v = ((const float4*)(x + (size_t)row * 1024))[tid];
    float s  = v.x + v.y + v.z + v.w;
    float ss = v.x * v.x + v.y * v.y + v.z * v.z + v.w * v.w;
    #pragma unroll
    for (int off = 32; off > 0; off >>= 1) {
        s  += __shfl_down(s, off);
        ss += __shfl_down(ss, off);
    }
    __shared__ float red[8];
    if ((tid & 63) == 0) { red[tid >> 6] = s; red[4 + (tid >> 6)] = ss; }
    __syncthreads();
    float S  = red[0] + red[1] + red[2] + red[3];
    float SS = red[4] + red[5] + red[6] + red[7];
    float mu  = S * (1.0f / 1024.0f);
    float var = SS * (1.0f / 1024.0f) - mu * mu;
    float rs  = rsqrtf(var + 1e-5f);
    float4 g4 = ((const float4*)gw)[tid];
    float4 b4 = ((const float4*)bw)[tid];
    u16* o = out + (size_t)row * 1024 + tid * 4;
    o[0] = f2bf((v.x - mu) * rs * g4.x + b4.x);
    o[1] = f2bf((v.y - mu) * rs * g4.y + b4.y);
    o[2] = f2bf((v.z - mu) * rs * g4.z + b4.z);
    o[3] = f2bf((v.w - mu) * rs * g4.w + b4.w);
}

// ---------------- GEMM modes ------------------------------------------------
#define MODE_BF16      0   // out bf16 = acc + bias
#define MODE_BF16_GELU 1   // out bf16 = gelu(acc + bias), tanh-approx gelu
#define MODE_F32_RES   2   // out f32  = acc + bias + res
#define MODE_QKV       3   // cols<2048: bf16 like MODE_BF16; cols>=2048: V^T to vt

// ======================= gemm8: 256x256 8-phase (R9, passed) ================
#define G8_BUF1 32768      // u16 offset of buffer 1 (64 KiB per buffer)
#define G8_LDS_BYTES 131072

#define SB()    __builtin_amdgcn_sched_barrier(0)
#define BARR()  do { __builtin_amdgcn_s_barrier(); SB(); } while (0)
#define GATE2() do { asm volatile("s_waitcnt vmcnt(2)" ::: "memory"); SB(); } while (0)
#define WL0()   do { asm volatile("s_waitcnt lgkmcnt(0)" ::: "memory"); SB(); } while (0)

#define RDA(DST, BUFOFF, MH) \
    _Pragma("unroll") \
    for (int mt = 0; mt < 4; ++mt) \
        _Pragma("unroll") \
        for (int ks = 0; ks < 2; ++ks) \
            DST[mt][ks] = *(const short8*)&lds[(BUFOFF) + \
                (size_t)(wr * 128 + (MH) * 64 + mt * 16 + lc) * 64 + \
                (((ks * 4 + lg) ^ (lc & 7)) * 8)];

#define RDB(DST, BUFOFF, NH) \
    _Pragma("unroll") \
    for (int nn = 0; nn < 2; ++nn) \
        _Pragma("unroll") \
        for (int ks = 0; ks < 2; ++ks) \
            DST[nn][ks] = *(const short8*)&lds[(BUFOFF) + 16384 + \
                (size_t)(wc * 64 + (NH) * 32 + nn * 16 + lc) * 64 + \
                (((ks * 4 + lg) ^ (lc & 7)) * 8)];

#define MMAQ(MH, NH, FA, FB) \
    __builtin_amdgcn_s_setprio(1); \
    _Pragma("unroll") \
    for (int ks = 0; ks < 2; ++ks) \
        _Pragma("unroll") \
        for (int mt = 0; mt < 4; ++mt) \
            _Pragma("unroll") \
            for (int nn = 0; nn < 2; ++nn) \
                acc[(MH) * 4 + mt][(NH) * 2 + nn] = \
                    __builtin_amdgcn_mfma_f32_16x16x32_bf16( \
                        FA[mt][ks], FB[nn][ks], acc[(MH) * 4 + mt][(NH) * 2 + nn], 0, 0, 0); \
    __builtin_amdgcn_s_setprio(0);

template<int MODE>
__global__ __launch_bounds__(512, 2) void gemm8_kernel(
    const u16* __restrict__ A, const u16* __restrict__ Bt,
    const float* __restrict__ bias, const float* __restrict__ res,
    void* __restrict__ outv, u16* __restrict__ vt,
    int M, int N, int lda, int ldb, int K)
{
    extern __shared__ u16 lds[];   // 2 x 64 KiB: [A 256x64 | B 256x64] per buf
    const int tid = threadIdx.x;
    const int wave = tid >> 6, lane = tid & 63;
    const int lg = lane >> 4, lc = lane & 15;
    // T1: m204 bijective XCD swizzle
    const int nx = gridDim.x, nwg = nx * gridDim.y;
    const int orig = blockIdx.y * nx + blockIdx.x;
    const int q = nwg >> 3, r = nwg & 7, xc = orig & 7, oo = orig >> 3;
    const int sid = (xc < r ? xc * (q + 1) : r * (q + 1) + (xc - r) * q) + oo;
    const int m0 = (sid / nx) * 256, n0 = (sid % nx) * 256;
    const int wr = wave >> 2, wc = wave & 3;   // 2 x 4 wave grid

    floatx4 acc[8][4];
    #pragma unroll
    for (int i = 0; i < 8; ++i)
        #pragma unroll
        for (int j = 0; j < 4; ++j) acc[i][j] = floatx4{0.f, 0.f, 0.f, 0.f};

    const int srow = lane >> 3;                 // row within 8-row group
    const int schunk = (lane & 7) ^ srow;       // pre-swizzled global chunk

    const u16* Abase = A  + (size_t)(m0 + wave * 8 + srow) * lda + schunk * 8;
    const u16* Bbase = Bt + (size_t)(n0 + wave * 8 + srow) * ldb + schunk * 8;

    // stage one half-tile (128 rows x BK=64) = 2 global_load_lds per thread.
    auto stageH = [&](int b, int o, int h, int kk) {
        if (o == 0) {
            const u16* src = Abase + (size_t)h * 128 * lda + kk;
            u16* dst = lds + b * G8_BUF1 + h * 8192 + wave * 512;
            __builtin_amdgcn_global_load_lds(GLB(src), LDSP(dst), 16, 0, 0);
            __builtin_amdgcn_global_load_lds(GLB(src + (size_t)64 * lda), LDSP(dst + 4096), 16, 0, 0);
        } else {
            const u16* src = Bbase + (size_t)h * 128 * ldb + kk;
            u16* dst = lds + b * G8_BUF1 + 16384 + h * 8192 + wave * 512;
            __builtin_amdgcn_global_load_lds(GLB(src), LDSP(dst), 16, 0, 0);
            __builtin_amdgcn_global_load_lds(GLB(src + (size_t)64 * ldb), LDSP(dst + 4096), 16, 0, 0);
        }
    };

    const int nt = K >> 6;   // K-tiles (K multiple of 128)

    // prologue: tile0 all 4 halves -> buf0; tile1 A-half0 -> buf1 (10 loads);
    // gate drains tile0's 8, leaves tile1-A0' in flight.
    stageH(0, 0, 0, 0); stageH(0, 0, 1, 0); stageH(0, 1, 0, 0); stageH(0, 1, 1, 0);
    stageH(1, 0, 0, 64);
    GATE2(); BARR();

    short8 fa0[4][2], fa1[4][2], fb0[2][2], fb1[2][2];

    for (int t0 = 0; t0 < nt; t0 += 2) {
        const int kk1 = (t0 + 1) * 64;                              // always valid
        const int kk2 = ((t0 + 2 < nt) ? t0 + 2 : nt - 1) * 64;     // clamp (count-preserving)
        const int kk3 = ((t0 + 3 < nt) ? t0 + 3 : nt - 1) * 64;
        // ---- P0: stage A1'(b1,t+1); RD fa0,fb0(b0) pre-barrier; Q00
        stageH(1, 0, 1, kk1);
        RDA(fa0, 0, 0) RDB(fb0, 0, 0) SB();
        BARR(); WL0();
        MMAQ(0, 0, fa0, fb0)
        // ---- P1: stage B0'(b1,t+1); RD fa1(b0); Q10
        stageH(1, 1, 0, kk1);
        RDA(fa1, 0, 1) SB();
        BARR(); WL0();
        MMAQ(1, 0, fa1, fb0)
        // ---- P2: stage B1'(b1,t+1); RD fb1(b0); Q11
        stageH(1, 1, 1, kk1);
        RDB(fb1, 0, 1) SB();
        BARR(); WL0();
        MMAQ(1, 1, fa1, fb1)
        // ---- P3: stage A0(b0,t+2); GATE vmcnt(2) certifies b1 tile t+1; Q01
        stageH(0, 0, 0, kk2); GATE2();
        BARR();
        MMAQ(0, 1, fa0, fb1)
        // ---- P4: stage A1+B0(b0,t+2); RD fa0,fb0(b1); Q00'
        stageH(0, 0, 1, kk2); stageH(0, 1, 0, kk2);
        RDA(fa0, G8_BUF1, 0) RDB(fb0, G8_BUF1, 0) SB();
        BARR(); WL0();
        MMAQ(0, 0, fa0, fb0)
        // ---- P5: stage B1(b0,t+2); RD fa1(b1); Q10'
        stageH(0, 1, 1, kk2);
        RDA(fa1, G8_BUF1, 1) SB();
        BARR(); WL0();
        MMAQ(1, 0, fa1, fb0)
        // ---- P6: (no stage); RD fb1(b1); Q11'
        RDB(fb1, G8_BUF1, 1) SB();
        BARR(); WL0();
        MMAQ(1, 1, fa1, fb1)
        // ---- P7: stage A0'(b1,t+3); GATE vmcnt(2) certifies b0 tile t+2; Q01'
        stageH(1, 0, 0, kk3); GATE2();
        BARR();
        MMAQ(0, 1, fa0, fb1)
    }
    // drain pending (clamped) stages before the wave can retire
    asm volatile("s_waitcnt vmcnt(0)" ::: "memory");

    // epilogue: C/D layout col=lane&15, row=(lane>>4)*4+reg (HW-verified)
    if (MODE == MODE_QKV && n0 >= 2048) {
        // V columns -> vt[b][h*64+d][token], token contiguous (8B packed)
        #pragma unroll
        for (int mt = 0; mt < 8; ++mt) {
            #pragma unroll
            for (int nn = 0; nn < 4; ++nn) {
                const int col = n0 + wc * 64 + nn * 16 + lc;
                const float bv = bias[col];
                const int hd = col - 2048;         // h*64 + d
                const int rowbase = m0 + wr * 128 + mt * 16 + lg * 4;
                const int b = rowbase >> 10, token = rowbase & 1023;
                float v0 = acc[mt][nn][0] + bv, v1 = acc[mt][nn][1] + bv;
                float v2 = acc[mt][nn][2] + bv, v3 = acc[mt][nn][3] + bv;
                uint2 pk = {pack2(v0, v1), pack2(v2, v3)};
                *(uint2*)&vt[((size_t)b * 1024 + hd) * 1024 + token] = pk;
            }
        }
        return;
    }
    #pragma unroll
    for (int mt = 0; mt < 8; ++mt) {
        #pragma unroll
        for (int nn = 0; nn < 4; ++nn) {
            const int col = n0 + wc * 64 + nn * 16 + lc;
            const float bv = bias[col];
            #pragma unroll
            for (int r = 0; r < 4; ++r) {
                const int row = m0 + wr * 128 + mt * 16 + lg * 4 + r;
                float v = acc[mt][nn][r] + bv;
                if (MODE == MODE_BF16 || MODE == MODE_QKV) {
                    ((u16*)outv)[(size_t)row * N + col] = f2bf(v);
                } else if (MODE == MODE_BF16_GELU) {
                    ((u16*)outv)[(size_t)row * N + col] = f2bf(fast_gelu(v));
                } else {  // MODE_F32_RES
                    ((float*)outv)[(size_t)row * N + col] = v + res[(size_t)row * N + col];
                }
            }
        }
    }
}

// ======================= gemm4: 128x128 counted (R10, passed) ===============
#define G4_BUFSZ 16384     // u16 per buffer: 128*64 (A) + 128*64 (B)
#define G4_LDS_BYTES 65536

template<int MODE>
__global__ __launch_bounds__(256, 2) void gemm4_kernel(
    const u16* __restrict__ A, const u16* __restrict__ Bt,
    const float* __restrict__ bias, const float* __restrict__ res,
    void* __restrict__ outv, u16* __restrict__ vt,
    int M, int N, int lda, int ldb, int K)
{
    extern __shared__ u16 lds[];   // 2 * G4_BUFSZ
    const int tid = threadIdx.x;
    const int wave = tid >> 6, lane = tid & 63;
    const int lg = lane >> 4, lc = lane & 15;
    const int nx = gridDim.x, nwg = nx * gridDim.y;
    const int orig = blockIdx.y * nx + blockIdx.x;
    const int q = nwg >> 3, r = nwg & 7, xc = orig & 7, oo = orig >> 3;
    const int sid = (xc < r ? xc * (q + 1) : r * (q + 1) + (xc - r) * q) + oo;
    const int m0 = (sid / nx) * 128, n0 = (sid % nx) * 128;
    const int wr = wave >> 1, wc = wave & 1;   // 2 x 2 wave grid

    floatx4 acc[4][4];
    #pragma unroll
    for (int i = 0; i < 4; ++i)
        #pragma unroll
        for (int j = 0; j < 4; ++j) acc[i][j] = floatx4{0.f, 0.f, 0.f, 0.f};

    const int srow = lane >> 3;
    const int schunk = (lane & 7) ^ srow;

    const u16* Agl = A  + (size_t)(m0 + wave * 32 + srow) * lda + schunk * 8;
    const u16* Bgl = Bt + (size_t)(n0 + wave * 32 + srow) * ldb + schunk * 8;
    const size_t a8 = (size_t)8 * lda, b8 = (size_t)8 * ldb;

    const int nt = K >> 6;
    auto stage = [&](int b, int kk) {   // exactly 8 VMEM ops per wave
        u16* base = lds + b * G4_BUFSZ;
        #pragma unroll
        for (int j = 0; j < 4; ++j)
            __builtin_amdgcn_global_load_lds(GLB(Agl + kk + j * a8),
                                             LDSP(base + (wave * 4 + j) * 512), 16, 0, 0);
        #pragma unroll
        for (int j = 0; j < 4; ++j)
            __builtin_amdgcn_global_load_lds(GLB(Bgl + kk + j * b8),
                                             LDSP(base + 8192 + (wave * 4 + j) * 512), 16, 0, 0);
    };

    stage(0, 0);
    stage(1, 64);
    asm volatile("s_waitcnt vmcnt(8)" ::: "memory");
    __builtin_amdgcn_s_barrier();
    __builtin_amdgcn_sched_barrier(0);

    int cur = 0;
    for (int t = 0; t < nt; ++t) {
        const u16* Ab = lds + cur * G4_BUFSZ;
        const u16* Bb = Ab + 8192;
        #pragma unroll
        for (int ks = 0; ks < 2; ++ks) {
            short8 fa[4], fb[4];
            #pragma unroll
            for (int mt = 0; mt < 4; ++mt)
                fa[mt] = *(const short8*)&Ab[(wr * 64 + mt * 16 + lc) * 64 +
                                             (((ks * 4 + lg) ^ (lc & 7)) * 8)];
            #pragma unroll
            for (int nn = 0; nn < 4; ++nn)
                fb[nn] = *(const short8*)&Bb[(wc * 64 + nn * 16 + lc) * 64 +
                                             (((ks * 4 + lg) ^ (lc & 7)) * 8)];
            __builtin_amdgcn_s_setprio(1);
            #pragma unroll
            for (int mt = 0; mt < 4; ++mt)
                #pragma unroll
                for (int nn = 0; nn < 4; ++nn)
                    acc[mt][nn] = __builtin_amdgcn_mfma_f32_16x16x32_bf16(
                        fa[mt], fb[nn], acc[mt][nn], 0, 0, 0);
            __builtin_amdgcn_s_setprio(0);
        }
        asm volatile("s_waitcnt lgkmcnt(0)" ::: "memory");
        __builtin_amdgcn_s_barrier();
        __builtin_amdgcn_sched_barrier(0);
        {
            const int tn = (t + 2 < nt) ? t + 2 : nt - 1;
            stage(cur, tn << 6);
        }
        asm volatile("s_waitcnt vmcnt(8)" ::: "memory");
        __builtin_amdgcn_s_barrier();
        __builtin_amdgcn_sched_barrier(0);
        cur ^= 1;
    }
    asm volatile("s_waitcnt vmcnt(0)" ::: "memory");

    #pragma unroll
    for (int mt = 0; mt < 4; ++mt) {
        #pragma unroll
        for (int nn = 0; nn < 4; ++nn) {
            const int col = n0 + wc * 64 + nn * 16 + lc;
            const float bv = bias[col];
            #pragma unroll
            for (int r = 0; r < 4; ++r) {
                const int row = m0 + wr * 64 + mt * 16 + lg * 4 + r;
                float v = acc[mt][nn][r] + bv;
                if (MODE == MODE_BF16) {
                    ((u16*)outv)[(size_t)row * N + col] = f2bf(v);
                } else if (MODE == MODE_BF16_GELU) {
                    ((u16*)outv)[(size_t)row * N + col] = f2bf(fast_gelu(v));
                } else {  // MODE_F32_RES
                    ((float*)outv)[(size_t)row * N + col] = v + res[(size_t)row * N + col];
                }
            }
        }
    }
}

// ---------------- Flash attention (S^T formulation, pipelined K/V) ----------
// Double-buffered K/V with the gemm4-proven counted-vmcnt ledger: 4 loads per
// wave per iter; {compute buf[cur]; lgkmcnt(0); barrier; stage kt+2 -> cur;
// vmcnt(4); barrier}. Q-LDS aliased with Ps (wave-private rows only).
__global__ __launch_bounds__(256) void attn_kernel(
    const u16* __restrict__ qkv, const u16* __restrict__ vtg, u16* __restrict__ out)
{
    const int bid = blockIdx.x;
    const int g = ((bid >> 7) << 3) | (bid & 7);   // (b,h) id, 0..127
    const int qt = (bid >> 3) & 15;
    const int h = g & 15, b = g >> 4;
    const int tid = threadIdx.x, wave = tid >> 6, lane = tid & 63;
    const int lg = lane >> 4, lc = lane & 15;

    __shared__ __attribute__((aligned(16))) u16 Ks[2][64 * 64];
    __shared__ __attribute__((aligned(16))) u16 Vts[2][64 * 64]; // [d][key]
    __shared__ __attribute__((aligned(16))) u16 QPs[64 * 64];    // Q, then P^T

    const int q0 = qt * 64;
    const size_t hb = ((size_t)b * 1024) * 3072 + h * 64;
    const u16* vhead = vtg + ((size_t)b * 1024 + h * 64) * 1024;
    const int srow = lane >> 3;
    const int schunk = (lane & 7) ^ srow;   // swizzled source chunk

    // stage Q tile [64 q][64 d] (wave-private rows: wave*16 .. +15)
    {
        const u16* Qg = qkv + hb + (size_t)(q0 + wave * 16 + srow) * 3072 + schunk * 8;
        u16* Qw = &QPs[wave * 1024];
        __builtin_amdgcn_global_load_lds(GLB(Qg), LDSP(Qw), 16, 0, 0);
        __builtin_amdgcn_global_load_lds(GLB(Qg + (size_t)8 * 3072), LDSP(Qw + 512), 16, 0, 0);
    }
    // 4 loads per buf per wave (2 K + 2 V)
    auto stageKV = [&](int buf, int kt) {
        const u16* Kg = qkv + hb + 1024 +
            (size_t)(kt * 64 + wave * 16 + srow) * 3072 + schunk * 8;
        u16* Kw = &Ks[buf][wave * 1024];
        __builtin_amdgcn_global_load_lds(GLB(Kg), LDSP(Kw), 16, 0, 0);
        __builtin_amdgcn_global_load_lds(GLB(Kg + (size_t)8 * 3072), LDSP(Kw + 512), 16, 0, 0);
        const u16* Vg = vhead + (size_t)(wave * 16 + srow) * 1024 + kt * 64 + schunk * 8;
        u16* Vw = &Vts[buf][wave * 1024];
        __builtin_amdgcn_global_load_lds(GLB(Vg), LDSP(Vw), 16, 0, 0);
        __builtin_amdgcn_global_load_lds(GLB(Vg + (size_t)8 * 1024), LDSP(Vw + 512), 16, 0, 0);
    };
    // prologue: Q(2) + buf0(4) + buf1(4) = 10 outstanding; vmcnt(4) drains
    // Q+buf0 (FIFO); barrier -> Q and buf0 collectively visible.
    stageKV(0, 0);
    stageKV(1, 1);
    asm volatile("s_waitcnt vmcnt(4)" ::: "memory");
    __builtin_amdgcn_s_barrier();
    __builtin_amdgcn_sched_barrier(0);

    short8 aq[2];   // B-operand: q = wave*16+lc (own rows), d = ks*32 + quad*8
    aq[0] = *(const short8*)&QPs[(wave * 16 + lc) * 64 + (((0 + lg) ^ (lc & 7)) * 8)];
    aq[1] = *(const short8*)&QPs[(wave * 16 + lc) * 64 + (((4 + lg) ^ (lc & 7)) * 8)];
    // aq is waited (lgkm) before the first MFMA below; first Ps write to the
    // same rows comes after those MFMAs in program order -> alias safe.

    floatx4 o[4];   // O^T tiles: d = dt*16 + lg*4 + r, q = wave*16+lc
    #pragma unroll
    for (int dt = 0; dt < 4; ++dt) o[dt] = floatx4{0.f, 0.f, 0.f, 0.f};
    float mprev = -INFINITY, lsum = 0.f;
    const float sc = 0.125f; // 1/sqrt(64)

    int cur = 0;
    for (int kt = 0; kt < 16; ++kt) {
        // S^T = K Q^T : st[nt][r] -> key = nt*16 + lg*4 + r, q = wave*16+lc
        floatx4 st[4];
        #pragma unroll
        for (int nt = 0; nt < 4; ++nt) st[nt] = floatx4{0.f, 0.f, 0.f, 0.f};
        #pragma unroll
        for (int ks = 0; ks < 2; ++ks)
            #pragma unroll
            for (int nt = 0; nt < 4; ++nt) {
                short8 fk = *(const short8*)&Ks[cur][(nt * 16 + lc) * 64 +
                                                    (((ks * 4 + lg) ^ (lc & 7)) * 8)];
                st[nt] = __builtin_amdgcn_mfma_f32_16x16x32_bf16(fk, aq[ks], st[nt], 0, 0, 0);
            }

        // online softmax, scalar state per lane (one q per lane)
        float m = st[0][0];
        #pragma unroll
        for (int nt = 0; nt < 4; ++nt)
            #pragma unroll
            for (int r = 0; r < 4; ++r) m = fmaxf(m, st[nt][r]);
        m = fmaxf(m, __shfl_xor(m, 16));
        m = fmaxf(m, __shfl_xor(m, 32));
        float mn = fmaxf(mprev, m * sc);
        float aexp = __expf(mprev - mn);
        mprev = mn;

        const int q = wave * 16 + lc;
        float rs = 0.f;
        #pragma unroll
        for (int nt = 0; nt < 4; ++nt) {
            float p0 = __expf(st[nt][0] * sc - mn);
            float p1 = __expf(st[nt][1] * sc - mn);
            float p2 = __expf(st[nt][2] * sc - mn);
            float p3 = __expf(st[nt][3] * sc - mn);
            rs += (p0 + p1) + (p2 + p3);
            // P^T[q][key], keys nt*16 + lg*4 .. +3 contiguous -> b64 write
            const int c16 = nt * 2 + (lg >> 1);
            uint2 pk = {pack2(p0, p1), pack2(p2, p3)};
            *(uint2*)&QPs[q * 64 + ((c16 ^ (lc & 7)) * 8) + (lg & 1) * 4] = pk;
        }
        rs += __shfl_xor(rs, 16);
        rs += __shfl_xor(rs, 32);
        lsum = lsum * aexp + rs;
        #pragma unroll
        for (int dt = 0; dt < 4; ++dt)
            #pragma unroll
            for (int r = 0; r < 4; ++r) o[dt][r] *= aexp;

        // O^T += V^T P^T  (wave-private QPs rows -> no barrier needed)
        #pragma unroll
        for (int ks = 0; ks < 2; ++ks) {
            short8 fp = *(const short8*)&QPs[q * 64 + (((ks * 4 + lg) ^ (lc & 7)) * 8)];
            #pragma unroll
            for (int dt = 0; dt < 4; ++dt) {
                short8 fv = *(const short8*)&Vts[cur][(dt * 16 + lc) * 64 +
                                                      (((ks * 4 + lg) ^ (lc & 7)) * 8)];
                o[dt] = __builtin_amdgcn_mfma_f32_16x16x32_bf16(fv, fp, o[dt], 0, 0, 0);
            }
        }

        // ledger (gemm4-proven): all my LDS reads of buf[cur] done; join; then
        // overwrite buf[cur] with tile kt+2; counted wait certifies buf[cur^1]
        // (tile kt+1, oldest 4) landed in every wave; kt+2's stay in flight.
        asm volatile("s_waitcnt lgkmcnt(0)" ::: "memory");
        __builtin_amdgcn_s_barrier();
        __builtin_amdgcn_sched_barrier(0);
        {
            const int tn = (kt + 2 < 16) ? kt + 2 : 15;   // clamp, count-exact
            stageKV(cur, tn);
        }
        asm volatile("s_waitcnt vmcnt(4)" ::: "memory");
        __builtin_amdgcn_s_barrier();
        __builtin_amdgcn_sched_barrier(0);
        cur ^= 1;
    }
    asm volatile("s_waitcnt vmcnt(0)" ::: "memory");  // drain clamped stages

    // epilogue: out[b, q, h*64 + d], d contiguous in r -> 8B packed stores
    const float rl = 1.0f / lsum;
    const int q = q0 + wave * 16 + lc;
    #pragma unroll
    for (int dt = 0; dt < 4; ++dt) {
        uint2 pk = {pack2(o[dt][0] * rl, o[dt][1] * rl),
                    pack2(o[dt][2] * rl, o[dt][3] * rl)};
        *(uint2*)&out[((size_t)b * 1024 + q) * 1024 + h * 64 + dt * 16 + lg * 4] = pk;
    }
}

// ---------------------------------------------------------------------------
extern "C" void kernel_launch(void* const* d_in, const int* in_sizes, int n_in,
                              void* d_out, int out_size, void* d_ws, size_t ws_size,
                              hipStream_t stream)
{
    const float* x      = (const float*)d_in[0];
    const float* ln1_g  = (const float*)d_in[1];
    const float* ln1_b  = (const float*)d_in[2];
    const float* w_qkv  = (const float*)d_in[3];
    const float* b_qkv  = (const float*)d_in[4];
    const float* w_proj = (const float*)d_in[5];
    const float* b_proj = (const float*)d_in[6];
    const float* ln2_g  = (const float*)d_in[7];
    const float* ln2_b  = (const float*)d_in[8];
    const float* w_fc1  = (const float*)d_in[9];
    const float* b_fc1  = (const float*)d_in[10];
    const float* w_fc2  = (const float*)d_in[11];
    const float* b_fc2  = (const float*)d_in[12];
    float* outp = (float*)d_out;

    char* ws = (char*)d_ws;
    size_t off = 0;
    auto alloc = [&](size_t bytes) { void* p = ws + off; off += (bytes + 255) & ~(size_t)255; return p; };
    u16*  wqkvT  = (u16*)alloc((size_t)3072 * 1024 * 2);
    u16*  wprojT = (u16*)alloc((size_t)1024 * 1024 * 2);
    u16*  wfc1T  = (u16*)alloc((size_t)4096 * 1024 * 2);
    u16*  wfc2T  = (u16*)alloc((size_t)1024 * 4096 * 2);
    u16*  hbuf   = (u16*)alloc((size_t)8192 * 1024 * 2);  // LN1 out, later LN2 out
    u16*  big    = (u16*)alloc((size_t)8192 * 4096 * 2);  // qk (stride 3072), later mlp hidden
    u16*  vtbuf  = (u16*)alloc((size_t)8 * 1024 * 1024 * 2); // V^T [b][h*64+d][token]
    u16*  attno  = (u16*)alloc((size_t)8192 * 1024 * 2);
    float* x2    = (float*)alloc((size_t)8192 * 1024 * 4);

    static bool attr_done = []{
        hipFuncSetAttribute(reinterpret_cast<const void*>(gemm8_kernel<MODE_QKV>),
                            hipFuncAttributeMaxDynamicSharedMemorySize, G8_LDS_BYTES);
        hipFuncSetAttribute(reinterpret_cast<const void*>(gemm8_kernel<MODE_BF16_GELU>),
                            hipFuncAttributeMaxDynamicSharedMemorySize, G8_LDS_BYTES);
        hipFuncSetAttribute(reinterpret_cast<const void*>(gemm4_kernel<MODE_F32_RES>),
                            hipFuncAttributeMaxDynamicSharedMemorySize, G4_LDS_BYTES);
        return true;
    }();
    (void)attr_done;

    dim3 tb(32, 8);
    transpose_cast_kernel<<<dim3(3072 / 32, 1024 / 32), tb, 0, stream>>>(w_qkv,  wqkvT,  1024, 3072);
    transpose_cast_kernel<<<dim3(1024 / 32, 1024 / 32), tb, 0, stream>>>(w_proj, wprojT, 1024, 1024);
    transpose_cast_kernel<<<dim3(4096 / 32, 1024 / 32), tb, 0, stream>>>(w_fc1,  wfc1T,  1024, 4096);
    transpose_cast_kernel<<<dim3(1024 / 32, 4096 / 32), tb, 0, stream>>>(w_fc2,  wfc2T,  4096, 1024);

    ln_kernel<<<8192, 256, 0, stream>>>(x, ln1_g, ln1_b, hbuf);
    gemm8_kernel<MODE_QKV><<<dim3(3072 / 256, 8192 / 256), 512, G8_LDS_BYTES, stream>>>(
        hbuf, wqkvT, b_qkv, nullptr, big, vtbuf, 8192, 3072, 1024, 1024, 1024);
    attn_kernel<<<2048, 256, 0, stream>>>(big, vtbuf, attno);
    gemm4_kernel<MODE_F32_RES><<<dim3(1024 / 128, 8192 / 128), 256, G4_LDS_BYTES, stream>>>(
        attno, wprojT, b_proj, x, x2, nullptr, 8192, 1024, 1024, 1024, 1024);
    ln_kernel<<<8192, 256, 0, stream>>>(x2, ln2_g, ln2_b, hbuf);
    gemm8_kernel<MODE_BF16_GELU><<<dim3(4096 / 256, 8192 / 256), 512, G8_LDS_BYTES, stream>>>(
        hbuf, wfc1T, b_fc1, nullptr, big, nullptr, 8192, 4096, 1024, 1024, 1024);
    gemm4_kernel<MODE_F32_RES><<<dim3(1024 / 128, 8192 / 128), 256, G4_LDS_BYTES, stream>>>(
        big, wfc2T, b_fc2, x2, outp, nullptr, 8192, 1024, 4096, 4096, 4096);
}

// Round 9
// 467.704 us; speedup vs baseline: 1.0154x; 1.0154x over previous
//
#include <hip/hip_runtime.h>
#include <cstdint>

// ---------------------------------------------------------------------------
// TransformerEncoderBlock: LN1 -> QKV -> MHA -> proj+res -> LN2 -> FC1+GELU
//                          -> FC2+res.  bf16 MFMA compute, fp32 accum.
// R14: attn VALU-trim (R13 counters: VALUBusy 66%, MfmaUtil 16%, HBM 6% ->
//   VALU-bound). All sync/ledger structure BYTE-IDENTICAL to harness-proven
//   R13 (attn) / R9 (gemm8) / R10 (gemm4). Local changes, attn only:
//   1) v_cvt_pk_bf16_f32 packing (T12): 8 instrs replace ~72 manual f2bf ops
//   2) exp2-domain softmax: sc2 = 0.125*log2e, exp2f = bare v_exp_f32
//      (saves the hidden x*log2e mul in __expf; identical softmax math)
//   3) defer-max (T13, THR=8): __all(pmax2-mprev2<=8) -> skip O-rescale,
//      keep old running max; P bounded by 2^8, fp32 accum safe
//   4) max3-tree tile max (clang fuses fmaxf(fmaxf,)) 15 -> ~8 ops
// ---------------------------------------------------------------------------

typedef unsigned short u16;
typedef short short8 __attribute__((ext_vector_type(8)));   // 8 bf16 = 4 VGPRs
typedef float floatx4 __attribute__((ext_vector_type(4)));  // MFMA C/D

#define GLB(p) ((const __attribute__((address_space(1))) void*)(p))
#define LDSP(p) ((__attribute__((address_space(3))) void*)(p))

__device__ __forceinline__ u16 f2bf(float f) {
    uint32_t u = __float_as_uint(f);
    u += 0x7fffu + ((u >> 16) & 1u);   // round-to-nearest-even
    return (u16)(u >> 16);
}
__device__ __forceinline__ uint32_t pack2(float a, float b) {
    return (uint32_t)f2bf(a) | ((uint32_t)f2bf(b) << 16);
}
__device__ __forceinline__ uint32_t cvtpk(float lo, float hi) {
    // packs lo -> [15:0], hi -> [31:16], RNE (T12 recipe; no builtin on gfx950)
    uint32_t r;
    asm("v_cvt_pk_bf16_f32 %0, %1, %2" : "=v"(r) : "v"(lo), "v"(hi));
    return r;
}
__device__ __forceinline__ float fmax3(float a, float b, float c) {
    return fmaxf(fmaxf(a, b), c);   // clang fuses to v_max3_f32
}
__device__ __forceinline__ float fast_gelu(float v) {
    // 0.5*v*(1+tanh(0.79788456*(v+0.044715 v^3))), tanh via exp+rcp, branchless
    float u = v * (0.7978845608f + 0.0356774081f * v * v);
    float e = __expf(2.0f * u);                       // v_exp_f32
    float th = 1.0f - 2.0f * __builtin_amdgcn_rcpf(e + 1.0f); // v_rcp_f32
    return 0.5f * v * (1.0f + th);
}

// ---------------- transpose + cast: W[K,N] f32 -> Wt[N,K] bf16 --------------
__global__ __launch_bounds__(256) void transpose_cast_kernel(
    const float* __restrict__ W, u16* __restrict__ Wt, int K, int N)
{
    __shared__ float tile[32][33];
    int n0 = blockIdx.x * 32, k0 = blockIdx.y * 32;
    int tx = threadIdx.x, ty = threadIdx.y; // block (32,8)
    #pragma unroll
    for (int i = 0; i < 4; ++i)
        tile[ty + i * 8][tx] = W[(size_t)(k0 + ty + i * 8) * N + n0 + tx];
    __syncthreads();
    #pragma unroll
    for (int i = 0; i < 4; ++i)
        Wt[(size_t)(n0 + ty + i * 8) * K + k0 + tx] = f2bf(tile[tx][ty + i * 8]);
}

// ---------------- LayerNorm: fp32 [rows,1024] -> bf16 ----------------------
__global__ __launch_bounds__(256) void ln_kernel(
    const float* __restrict__ x, const float* __restrict__ gw,
    const float* __restrict__ bw, u16* __restrict__ out)
{
    const int row = blockIdx.x, tid = threadIdx.x;
    float4 v = ((const float4*)(x + (size_t)row * 1024))[tid];
    float s  = v.x + v.y + v.z + v.w;
    float ss = v.x * v.x + v.y * v.y + v.z * v.z + v.w * v.w;
    #pragma unroll
    for (int off = 32; off > 0; off >>= 1) {
        s  += __shfl_down(s, off);
        ss += __shfl_down(ss, off);
    }
    __shared__ float red[8];
    if ((tid & 63) == 0) { red[tid >> 6] = s; red[4 + (tid >> 6)] = ss; }
    __syncthreads();
    float S  = red[0] + red[1] + red[2] + red[3];
    float SS = red[4] + red[5] + red[6] + red[7];
    float mu  = S * (1.0f / 1024.0f);
    float var = SS * (1.0f / 1024.0f) - mu * mu;
    float rs  = rsqrtf(var + 1e-5f);
    float4 g4 = ((const float4*)gw)[tid];
    float4 b4 = ((const float4*)bw)[tid];
    u16* o = out + (size_t)row * 1024 + tid * 4;
    o[0] = f2bf((v.x - mu) * rs * g4.x + b4.x);
    o[1] = f2bf((v.y - mu) * rs * g4.y + b4.y);
    o[2] = f2bf((v.z - mu) * rs * g4.z + b4.z);
    o[3] = f2bf((v.w - mu) * rs * g4.w + b4.w);
}

// ---------------- GEMM modes ------------------------------------------------
#define MODE_BF16      0   // out bf16 = acc + bias
#define MODE_BF16_GELU 1   // out bf16 = gelu(acc + bias), tanh-approx gelu
#define MODE_F32_RES   2   // out f32  = acc + bias + res
#define MODE_QKV       3   // cols<2048: bf16 like MODE_BF16; cols>=2048: V^T to vt

// ======================= gemm8: 256x256 8-phase (R9, passed) ================
#define G8_BUF1 32768      // u16 offset of buffer 1 (64 KiB per buffer)
#define G8_LDS_BYTES 131072

#define SB()    __builtin_amdgcn_sched_barrier(0)
#define BARR()  do { __builtin_amdgcn_s_barrier(); SB(); } while (0)
#define GATE2() do { asm volatile("s_waitcnt vmcnt(2)" ::: "memory"); SB(); } while (0)
#define WL0()   do { asm volatile("s_waitcnt lgkmcnt(0)" ::: "memory"); SB(); } while (0)

#define RDA(DST, BUFOFF, MH) \
    _Pragma("unroll") \
    for (int mt = 0; mt < 4; ++mt) \
        _Pragma("unroll") \
        for (int ks = 0; ks < 2; ++ks) \
            DST[mt][ks] = *(const short8*)&lds[(BUFOFF) + \
                (size_t)(wr * 128 + (MH) * 64 + mt * 16 + lc) * 64 + \
                (((ks * 4 + lg) ^ (lc & 7)) * 8)];

#define RDB(DST, BUFOFF, NH) \
    _Pragma("unroll") \
    for (int nn = 0; nn < 2; ++nn) \
        _Pragma("unroll") \
        for (int ks = 0; ks < 2; ++ks) \
            DST[nn][ks] = *(const short8*)&lds[(BUFOFF) + 16384 + \
                (size_t)(wc * 64 + (NH) * 32 + nn * 16 + lc) * 64 + \
                (((ks * 4 + lg) ^ (lc & 7)) * 8)];

#define MMAQ(MH, NH, FA, FB) \
    __builtin_amdgcn_s_setprio(1); \
    _Pragma("unroll") \
    for (int ks = 0; ks < 2; ++ks) \
        _Pragma("unroll") \
        for (int mt = 0; mt < 4; ++mt) \
            _Pragma("unroll") \
            for (int nn = 0; nn < 2; ++nn) \
                acc[(MH) * 4 + mt][(NH) * 2 + nn] = \
                    __builtin_amdgcn_mfma_f32_16x16x32_bf16( \
                        FA[mt][ks], FB[nn][ks], acc[(MH) * 4 + mt][(NH) * 2 + nn], 0, 0, 0); \
    __builtin_amdgcn_s_setprio(0);

template<int MODE>
__global__ __launch_bounds__(512, 2) void gemm8_kernel(
    const u16* __restrict__ A, const u16* __restrict__ Bt,
    const float* __restrict__ bias, const float* __restrict__ res,
    void* __restrict__ outv, u16* __restrict__ vt,
    int M, int N, int lda, int ldb, int K)
{
    extern __shared__ u16 lds[];   // 2 x 64 KiB: [A 256x64 | B 256x64] per buf
    const int tid = threadIdx.x;
    const int wave = tid >> 6, lane = tid & 63;
    const int lg = lane >> 4, lc = lane & 15;
    // T1: m204 bijective XCD swizzle
    const int nx = gridDim.x, nwg = nx * gridDim.y;
    const int orig = blockIdx.y * nx + blockIdx.x;
    const int q = nwg >> 3, r = nwg & 7, xc = orig & 7, oo = orig >> 3;
    const int sid = (xc < r ? xc * (q + 1) : r * (q + 1) + (xc - r) * q) + oo;
    const int m0 = (sid / nx) * 256, n0 = (sid % nx) * 256;
    const int wr = wave >> 2, wc = wave & 3;   // 2 x 4 wave grid

    floatx4 acc[8][4];
    #pragma unroll
    for (int i = 0; i < 8; ++i)
        #pragma unroll
        for (int j = 0; j < 4; ++j) acc[i][j] = floatx4{0.f, 0.f, 0.f, 0.f};

    const int srow = lane >> 3;                 // row within 8-row group
    const int schunk = (lane & 7) ^ srow;       // pre-swizzled global chunk

    const u16* Abase = A  + (size_t)(m0 + wave * 8 + srow) * lda + schunk * 8;
    const u16* Bbase = Bt + (size_t)(n0 + wave * 8 + srow) * ldb + schunk * 8;

    // stage one half-tile (128 rows x BK=64) = 2 global_load_lds per thread.
    auto stageH = [&](int b, int o, int h, int kk) {
        if (o == 0) {
            const u16* src = Abase + (size_t)h * 128 * lda + kk;
            u16* dst = lds + b * G8_BUF1 + h * 8192 + wave * 512;
            __builtin_amdgcn_global_load_lds(GLB(src), LDSP(dst), 16, 0, 0);
            __builtin_amdgcn_global_load_lds(GLB(src + (size_t)64 * lda), LDSP(dst + 4096), 16, 0, 0);
        } else {
            const u16* src = Bbase + (size_t)h * 128 * ldb + kk;
            u16* dst = lds + b * G8_BUF1 + 16384 + h * 8192 + wave * 512;
            __builtin_amdgcn_global_load_lds(GLB(src), LDSP(dst), 16, 0, 0);
            __builtin_amdgcn_global_load_lds(GLB(src + (size_t)64 * ldb), LDSP(dst + 4096), 16, 0, 0);
        }
    };

    const int nt = K >> 6;   // K-tiles (K multiple of 128)

    // prologue: tile0 all 4 halves -> buf0; tile1 A-half0 -> buf1 (10 loads);
    // gate drains tile0's 8, leaves tile1-A0' in flight.
    stageH(0, 0, 0, 0); stageH(0, 0, 1, 0); stageH(0, 1, 0, 0); stageH(0, 1, 1, 0);
    stageH(1, 0, 0, 64);
    GATE2(); BARR();

    short8 fa0[4][2], fa1[4][2], fb0[2][2], fb1[2][2];

    for (int t0 = 0; t0 < nt; t0 += 2) {
        const int kk1 = (t0 + 1) * 64;                              // always valid
        const int kk2 = ((t0 + 2 < nt) ? t0 + 2 : nt - 1) * 64;     // clamp (count-preserving)
        const int kk3 = ((t0 + 3 < nt) ? t0 + 3 : nt - 1) * 64;
        // ---- P0: stage A1'(b1,t+1); RD fa0,fb0(b0) pre-barrier; Q00
        stageH(1, 0, 1, kk1);
        RDA(fa0, 0, 0) RDB(fb0, 0, 0) SB();
        BARR(); WL0();
        MMAQ(0, 0, fa0, fb0)
        // ---- P1: stage B0'(b1,t+1); RD fa1(b0); Q10
        stageH(1, 1, 0, kk1);
        RDA(fa1, 0, 1) SB();
        BARR(); WL0();
        MMAQ(1, 0, fa1, fb0)
        // ---- P2: stage B1'(b1,t+1); RD fb1(b0); Q11
        stageH(1, 1, 1, kk1);
        RDB(fb1, 0, 1) SB();
        BARR(); WL0();
        MMAQ(1, 1, fa1, fb1)
        // ---- P3: stage A0(b0,t+2); GATE vmcnt(2) certifies b1 tile t+1; Q01
        stageH(0, 0, 0, kk2); GATE2();
        BARR();
        MMAQ(0, 1, fa0, fb1)
        // ---- P4: stage A1+B0(b0,t+2); RD fa0,fb0(b1); Q00'
        stageH(0, 0, 1, kk2); stageH(0, 1, 0, kk2);
        RDA(fa0, G8_BUF1, 0) RDB(fb0, G8_BUF1, 0) SB();
        BARR(); WL0();
        MMAQ(0, 0, fa0, fb0)
        // ---- P5: stage B1(b0,t+2); RD fa1(b1); Q10'
        stageH(0, 1, 1, kk2);
        RDA(fa1, G8_BUF1, 1) SB();
        BARR(); WL0();
        MMAQ(1, 0, fa1, fb0)
        // ---- P6: (no stage); RD fb1(b1); Q11'
        RDB(fb1, G8_BUF1, 1) SB();
        BARR(); WL0();
        MMAQ(1, 1, fa1, fb1)
        // ---- P7: stage A0'(b1,t+3); GATE vmcnt(2) certifies b0 tile t+2; Q01'
        stageH(1, 0, 0, kk3); GATE2();
        BARR();
        MMAQ(0, 1, fa0, fb1)
    }
    // drain pending (clamped) stages before the wave can retire
    asm volatile("s_waitcnt vmcnt(0)" ::: "memory");

    // epilogue: C/D layout col=lane&15, row=(lane>>4)*4+reg (HW-verified)
    if (MODE == MODE_QKV && n0 >= 2048) {
        // V columns -> vt[b][h*64+d][token], token contiguous (8B packed)
        #pragma unroll
        for (int mt = 0; mt < 8; ++mt) {
            #pragma unroll
            for (int nn = 0; nn < 4; ++nn) {
                const int col = n0 + wc * 64 + nn * 16 + lc;
                const float bv = bias[col];
                const int hd = col - 2048;         // h*64 + d
                const int rowbase = m0 + wr * 128 + mt * 16 + lg * 4;
                const int b = rowbase >> 10, token = rowbase & 1023;
                float v0 = acc[mt][nn][0] + bv, v1 = acc[mt][nn][1] + bv;
                float v2 = acc[mt][nn][2] + bv, v3 = acc[mt][nn][3] + bv;
                uint2 pk = {pack2(v0, v1), pack2(v2, v3)};
                *(uint2*)&vt[((size_t)b * 1024 + hd) * 1024 + token] = pk;
            }
        }
        return;
    }
    #pragma unroll
    for (int mt = 0; mt < 8; ++mt) {
        #pragma unroll
        for (int nn = 0; nn < 4; ++nn) {
            const int col = n0 + wc * 64 + nn * 16 + lc;
            const float bv = bias[col];
            #pragma unroll
            for (int r = 0; r < 4; ++r) {
                const int row = m0 + wr * 128 + mt * 16 + lg * 4 + r;
                float v = acc[mt][nn][r] + bv;
                if (MODE == MODE_BF16 || MODE == MODE_QKV) {
                    ((u16*)outv)[(size_t)row * N + col] = f2bf(v);
                } else if (MODE == MODE_BF16_GELU) {
                    ((u16*)outv)[(size_t)row * N + col] = f2bf(fast_gelu(v));
                } else {  // MODE_F32_RES
                    ((float*)outv)[(size_t)row * N + col] = v + res[(size_t)row * N + col];
                }
            }
        }
    }
}

// ======================= gemm4: 128x128 counted (R10, passed) ===============
#define G4_BUFSZ 16384     // u16 per buffer: 128*64 (A) + 128*64 (B)
#define G4_LDS_BYTES 65536

template<int MODE>
__global__ __launch_bounds__(256, 2) void gemm4_kernel(
    const u16* __restrict__ A, const u16* __restrict__ Bt,
    const float* __restrict__ bias, const float* __restrict__ res,
    void* __restrict__ outv, u16* __restrict__ vt,
    int M, int N, int lda, int ldb, int K)
{
    extern __shared__ u16 lds[];   // 2 * G4_BUFSZ
    const int tid = threadIdx.x;
    const int wave = tid >> 6, lane = tid & 63;
    const int lg = lane >> 4, lc = lane & 15;
    const int nx = gridDim.x, nwg = nx * gridDim.y;
    const int orig = blockIdx.y * nx + blockIdx.x;
    const int q = nwg >> 3, r = nwg & 7, xc = orig & 7, oo = orig >> 3;
    const int sid = (xc < r ? xc * (q + 1) : r * (q + 1) + (xc - r) * q) + oo;
    const int m0 = (sid / nx) * 128, n0 = (sid % nx) * 128;
    const int wr = wave >> 1, wc = wave & 1;   // 2 x 2 wave grid

    floatx4 acc[4][4];
    #pragma unroll
    for (int i = 0; i < 4; ++i)
        #pragma unroll
        for (int j = 0; j < 4; ++j) acc[i][j] = floatx4{0.f, 0.f, 0.f, 0.f};

    const int srow = lane >> 3;
    const int schunk = (lane & 7) ^ srow;

    const u16* Agl = A  + (size_t)(m0 + wave * 32 + srow) * lda + schunk * 8;
    const u16* Bgl = Bt + (size_t)(n0 + wave * 32 + srow) * ldb + schunk * 8;
    const size_t a8 = (size_t)8 * lda, b8 = (size_t)8 * ldb;

    const int nt = K >> 6;
    auto stage = [&](int b, int kk) {   // exactly 8 VMEM ops per wave
        u16* base = lds + b * G4_BUFSZ;
        #pragma unroll
        for (int j = 0; j < 4; ++j)
            __builtin_amdgcn_global_load_lds(GLB(Agl + kk + j * a8),
                                             LDSP(base + (wave * 4 + j) * 512), 16, 0, 0);
        #pragma unroll
        for (int j = 0; j < 4; ++j)
            __builtin_amdgcn_global_load_lds(GLB(Bgl + kk + j * b8),
                                             LDSP(base + 8192 + (wave * 4 + j) * 512), 16, 0, 0);
    };

    stage(0, 0);
    stage(1, 64);
    asm volatile("s_waitcnt vmcnt(8)" ::: "memory");
    __builtin_amdgcn_s_barrier();
    __builtin_amdgcn_sched_barrier(0);

    int cur = 0;
    for (int t = 0; t < nt; ++t) {
        const u16* Ab = lds + cur * G4_BUFSZ;
        const u16* Bb = Ab + 8192;
        #pragma unroll
        for (int ks = 0; ks < 2; ++ks) {
            short8 fa[4], fb[4];
            #pragma unroll
            for (int mt = 0; mt < 4; ++mt)
                fa[mt] = *(const short8*)&Ab[(wr * 64 + mt * 16 + lc) * 64 +
                                             (((ks * 4 + lg) ^ (lc & 7)) * 8)];
            #pragma unroll
            for (int nn = 0; nn < 4; ++nn)
                fb[nn] = *(const short8*)&Bb[(wc * 64 + nn * 16 + lc) * 64 +
                                             (((ks * 4 + lg) ^ (lc & 7)) * 8)];
            __builtin_amdgcn_s_setprio(1);
            #pragma unroll
            for (int mt = 0; mt < 4; ++mt)
                #pragma unroll
                for (int nn = 0; nn < 4; ++nn)
                    acc[mt][nn] = __builtin_amdgcn_mfma_f32_16x16x32_bf16(
                        fa[mt], fb[nn], acc[mt][nn], 0, 0, 0);
            __builtin_amdgcn_s_setprio(0);
        }
        asm volatile("s_waitcnt lgkmcnt(0)" ::: "memory");
        __builtin_amdgcn_s_barrier();
        __builtin_amdgcn_sched_barrier(0);
        {
            const int tn = (t + 2 < nt) ? t + 2 : nt - 1;
            stage(cur, tn << 6);
        }
        asm volatile("s_waitcnt vmcnt(8)" ::: "memory");
        __builtin_amdgcn_s_barrier();
        __builtin_amdgcn_sched_barrier(0);
        cur ^= 1;
    }
    asm volatile("s_waitcnt vmcnt(0)" ::: "memory");

    #pragma unroll
    for (int mt = 0; mt < 4; ++mt) {
        #pragma unroll
        for (int nn = 0; nn < 4; ++nn) {
            const int col = n0 + wc * 64 + nn * 16 + lc;
            const float bv = bias[col];
            #pragma unroll
            for (int r = 0; r < 4; ++r) {
                const int row = m0 + wr * 64 + mt * 16 + lg * 4 + r;
                float v = acc[mt][nn][r] + bv;
                if (MODE == MODE_BF16) {
                    ((u16*)outv)[(size_t)row * N + col] = f2bf(v);
                } else if (MODE == MODE_BF16_GELU) {
                    ((u16*)outv)[(size_t)row * N + col] = f2bf(fast_gelu(v));
                } else {  // MODE_F32_RES
                    ((float*)outv)[(size_t)row * N + col] = v + res[(size_t)row * N + col];
                }
            }
        }
    }
}

// ---------------- Flash attention (S^T formulation, pipelined K/V) ----------
// Sync structure identical to R13 (harness-proven). VALU-trimmed inner loop.
__global__ __launch_bounds__(256) void attn_kernel(
    const u16* __restrict__ qkv, const u16* __restrict__ vtg, u16* __restrict__ out)
{
    const int bid = blockIdx.x;
    const int g = ((bid >> 7) << 3) | (bid & 7);   // (b,h) id, 0..127
    const int qt = (bid >> 3) & 15;
    const int h = g & 15, b = g >> 4;
    const int tid = threadIdx.x, wave = tid >> 6, lane = tid & 63;
    const int lg = lane >> 4, lc = lane & 15;

    __shared__ __attribute__((aligned(16))) u16 Ks[2][64 * 64];
    __shared__ __attribute__((aligned(16))) u16 Vts[2][64 * 64]; // [d][key]
    __shared__ __attribute__((aligned(16))) u16 QPs[64 * 64];    // Q, then P^T

    const int q0 = qt * 64;
    const size_t hb = ((size_t)b * 1024) * 3072 + h * 64;
    const u16* vhead = vtg + ((size_t)b * 1024 + h * 64) * 1024;
    const int srow = lane >> 3;
    const int schunk = (lane & 7) ^ srow;   // swizzled source chunk

    // stage Q tile [64 q][64 d] (wave-private rows: wave*16 .. +15)
    {
        const u16* Qg = qkv + hb + (size_t)(q0 + wave * 16 + srow) * 3072 + schunk * 8;
        u16* Qw = &QPs[wave * 1024];
        __builtin_amdgcn_global_load_lds(GLB(Qg), LDSP(Qw), 16, 0, 0);
        __builtin_amdgcn_global_load_lds(GLB(Qg + (size_t)8 * 3072), LDSP(Qw + 512), 16, 0, 0);
    }
    // 4 loads per buf per wave (2 K + 2 V)
    auto stageKV = [&](int buf, int kt) {
        const u16* Kg = qkv + hb + 1024 +
            (size_t)(kt * 64 + wave * 16 + srow) * 3072 + schunk * 8;
        u16* Kw = &Ks[buf][wave * 1024];
        __builtin_amdgcn_global_load_lds(GLB(Kg), LDSP(Kw), 16, 0, 0);
        __builtin_amdgcn_global_load_lds(GLB(Kg + (size_t)8 * 3072), LDSP(Kw + 512), 16, 0, 0);
        const u16* Vg = vhead + (size_t)(wave * 16 + srow) * 1024 + kt * 64 + schunk * 8;
        u16* Vw = &Vts[buf][wave * 1024];
        __builtin_amdgcn_global_load_lds(GLB(Vg), LDSP(Vw), 16, 0, 0);
        __builtin_amdgcn_global_load_lds(GLB(Vg + (size_t)8 * 1024), LDSP(Vw + 512), 16, 0, 0);
    };
    // prologue: Q(2) + buf0(4) + buf1(4) = 10 outstanding; vmcnt(4) drains
    // Q+buf0 (FIFO); barrier -> Q and buf0 collectively visible.
    stageKV(0, 0);
    stageKV(1, 1);
    asm volatile("s_waitcnt vmcnt(4)" ::: "memory");
    __builtin_amdgcn_s_barrier();
    __builtin_amdgcn_sched_barrier(0);

    short8 aq[2];   // B-operand: q = wave*16+lc (own rows), d = ks*32 + quad*8
    aq[0] = *(const short8*)&QPs[(wave * 16 + lc) * 64 + (((0 + lg) ^ (lc & 7)) * 8)];
    aq[1] = *(const short8*)&QPs[(wave * 16 + lc) * 64 + (((4 + lg) ^ (lc & 7)) * 8)];

    floatx4 o[4];   // O^T tiles: d = dt*16 + lg*4 + r, q = wave*16+lc
    #pragma unroll
    for (int dt = 0; dt < 4; ++dt) o[dt] = floatx4{0.f, 0.f, 0.f, 0.f};
    // log2-domain online softmax: weights = 2^(s * sc2), sc2 = 0.125*log2(e)
    const float sc2 = 0.18033688011112042f;
    float mprev2 = -INFINITY, lsum = 0.f;

    int cur = 0;
    for (int kt = 0; kt < 16; ++kt) {
        // S^T = K Q^T : st[nt][r] -> key = nt*16 + lg*4 + r, q = wave*16+lc
        floatx4 st[4];
        #pragma unroll
        for (int nt = 0; nt < 4; ++nt) st[nt] = floatx4{0.f, 0.f, 0.f, 0.f};
        #pragma unroll
        for (int ks = 0; ks < 2; ++ks)
            #pragma unroll
            for (int nt = 0; nt < 4; ++nt) {
                short8 fk = *(const short8*)&Ks[cur][(nt * 16 + lc) * 64 +
                                                    (((ks * 4 + lg) ^ (lc & 7)) * 8)];
                st[nt] = __builtin_amdgcn_mfma_f32_16x16x32_bf16(fk, aq[ks], st[nt], 0, 0, 0);
            }

        // tile max via max3 tree (8 ops vs 15-op serial chain)
        float r0 = fmax3(st[0][0], st[0][1], st[0][2]);
        float r1 = fmax3(st[0][3], st[1][0], st[1][1]);
        float r2 = fmax3(st[1][2], st[1][3], st[2][0]);
        float r3 = fmax3(st[2][1], st[2][2], st[2][3]);
        float r4 = fmax3(st[3][0], st[3][1], st[3][2]);
        float m = fmaxf(fmax3(r0, r1, r2), fmax3(r3, r4, st[3][3]));
        m = fmaxf(m, __shfl_xor(m, 16));
        m = fmaxf(m, __shfl_xor(m, 32));
        const float pmax2 = m * sc2;

        // defer-max (T13, THR=8): skip rescale when max growth is small.
        // skip is wave-uniform (__all). P bounded by 2^8 when skipped.
        float mn2, aexp;
        const bool skip = __all(pmax2 - mprev2 <= 8.0f);
        if (skip) {
            mn2 = mprev2; aexp = 1.0f;
        } else {
            mn2 = fmaxf(mprev2, pmax2);
            aexp = exp2f(mprev2 - mn2);
            mprev2 = mn2;
        }

        const int q = wave * 16 + lc;
        float rs = 0.f;
        #pragma unroll
        for (int nt = 0; nt < 4; ++nt) {
            float p0 = exp2f(st[nt][0] * sc2 - mn2);
            float p1 = exp2f(st[nt][1] * sc2 - mn2);
            float p2 = exp2f(st[nt][2] * sc2 - mn2);
            float p3 = exp2f(st[nt][3] * sc2 - mn2);
            rs += (p0 + p1) + (p2 + p3);
            // P^T[q][key], keys nt*16 + lg*4 .. +3 contiguous -> b64 write
            const int c16 = nt * 2 + (lg >> 1);
            uint2 pk = {cvtpk(p0, p1), cvtpk(p2, p3)};
            *(uint2*)&QPs[q * 64 + ((c16 ^ (lc & 7)) * 8) + (lg & 1) * 4] = pk;
        }
        rs += __shfl_xor(rs, 16);
        rs += __shfl_xor(rs, 32);
        lsum = lsum * aexp + rs;
        if (!skip) {
            #pragma unroll
            for (int dt = 0; dt < 4; ++dt) o[dt] *= aexp;
        }

        // O^T += V^T P^T  (wave-private QPs rows -> no barrier needed)
        #pragma unroll
        for (int ks = 0; ks < 2; ++ks) {
            short8 fp = *(const short8*)&QPs[q * 64 + (((ks * 4 + lg) ^ (lc & 7)) * 8)];
            #pragma unroll
            for (int dt = 0; dt < 4; ++dt) {
                short8 fv = *(const short8*)&Vts[cur][(dt * 16 + lc) * 64 +
                                                      (((ks * 4 + lg) ^ (lc & 7)) * 8)];
                o[dt] = __builtin_amdgcn_mfma_f32_16x16x32_bf16(fv, fp, o[dt], 0, 0, 0);
            }
        }

        // ledger (gemm4-proven, R13-verbatim): compute cur; lgkmcnt(0); bar;
        // stage kt+2 -> cur; vmcnt(4); bar.
        asm volatile("s_waitcnt lgkmcnt(0)" ::: "memory");
        __builtin_amdgcn_s_barrier();
        __builtin_amdgcn_sched_barrier(0);
        {
            const int tn = (kt + 2 < 16) ? kt + 2 : 15;   // clamp, count-exact
            stageKV(cur, tn);
        }
        asm volatile("s_waitcnt vmcnt(4)" ::: "memory");
        __builtin_amdgcn_s_barrier();
        __builtin_amdgcn_sched_barrier(0);
        cur ^= 1;
    }
    asm volatile("s_waitcnt vmcnt(0)" ::: "memory");  // drain clamped stages

    // epilogue: out[b, q, h*64 + d], d contiguous in r -> 8B packed stores
    const float rl = 1.0f / lsum;
    const int q = q0 + wave * 16 + lc;
    #pragma unroll
    for (int dt = 0; dt < 4; ++dt) {
        uint2 pk = {cvtpk(o[dt][0] * rl, o[dt][1] * rl),
                    cvtpk(o[dt][2] * rl, o[dt][3] * rl)};
        *(uint2*)&out[((size_t)b * 1024 + q) * 1024 + h * 64 + dt * 16 + lg * 4] = pk;
    }
}

// ---------------------------------------------------------------------------
extern "C" void kernel_launch(void* const* d_in, const int* in_sizes, int n_in,
                              void* d_out, int out_size, void* d_ws, size_t ws_size,
                              hipStream_t stream)
{
    const float* x      = (const float*)d_in[0];
    const float* ln1_g  = (const float*)d_in[1];
    const float* ln1_b  = (const float*)d_in[2];
    const float* w_qkv  = (const float*)d_in[3];
    const float* b_qkv  = (const float*)d_in[4];
    const float* w_proj = (const float*)d_in[5];
    const float* b_proj = (const float*)d_in[6];
    const float* ln2_g  = (const float*)d_in[7];
    const float* ln2_b  = (const float*)d_in[8];
    const float* w_fc1  = (const float*)d_in[9];
    const float* b_fc1  = (const float*)d_in[10];
    const float* w_fc2  = (const float*)d_in[11];
    const float* b_fc2  = (const float*)d_in[12];
    float* outp = (float*)d_out;

    char* ws = (char*)d_ws;
    size_t off = 0;
    auto alloc = [&](size_t bytes) { void* p = ws + off; off += (bytes + 255) & ~(size_t)255; return p; };
    u16*  wqkvT  = (u16*)alloc((size_t)3072 * 1024 * 2);
    u16*  wprojT = (u16*)alloc((size_t)1024 * 1024 * 2);
    u16*  wfc1T  = (u16*)alloc((size_t)4096 * 1024 * 2);
    u16*  wfc2T  = (u16*)alloc((size_t)1024 * 4096 * 2);
    u16*  hbuf   = (u16*)alloc((size_t)8192 * 1024 * 2);  // LN1 out, later LN2 out
    u16*  big    = (u16*)alloc((size_t)8192 * 4096 * 2);  // qk (stride 3072), later mlp hidden
    u16*  vtbuf  = (u16*)alloc((size_t)8 * 1024 * 1024 * 2); // V^T [b][h*64+d][token]
    u16*  attno  = (u16*)alloc((size_t)8192 * 1024 * 2);
    float* x2    = (float*)alloc((size_t)8192 * 1024 * 4);

    static bool attr_done = []{
        hipFuncSetAttribute(reinterpret_cast<const void*>(gemm8_kernel<MODE_QKV>),
                            hipFuncAttributeMaxDynamicSharedMemorySize, G8_LDS_BYTES);
        hipFuncSetAttribute(reinterpret_cast<const void*>(gemm8_kernel<MODE_BF16_GELU>),
                            hipFuncAttributeMaxDynamicSharedMemorySize, G8_LDS_BYTES);
        hipFuncSetAttribute(reinterpret_cast<const void*>(gemm4_kernel<MODE_F32_RES>),
                            hipFuncAttributeMaxDynamicSharedMemorySize, G4_LDS_BYTES);
        return true;
    }();
    (void)attr_done;

    dim3 tb(32, 8);
    transpose_cast_kernel<<<dim3(3072 / 32, 1024 / 32), tb, 0, stream>>>(w_qkv,  wqkvT,  1024, 3072);
    transpose_cast_kernel<<<dim3(1024 / 32, 1024 / 32), tb, 0, stream>>>(w_proj, wprojT, 1024, 1024);
    transpose_cast_kernel<<<dim3(4096 / 32, 1024 / 32), tb, 0, stream>>>(w_fc1,  wfc1T,  1024, 4096);
    transpose_cast_kernel<<<dim3(1024 / 32, 4096 / 32), tb, 0, stream>>>(w_fc2,  wfc2T,  4096, 1024);

    ln_kernel<<<8192, 256, 0, stream>>>(x, ln1_g, ln1_b, hbuf);
    gemm8_kernel<MODE_QKV><<<dim3(3072 / 256, 8192 / 256), 512, G8_LDS_BYTES, stream>>>(
        hbuf, wqkvT, b_qkv, nullptr, big, vtbuf, 8192, 3072, 1024, 1024, 1024);
    attn_kernel<<<2048, 256, 0, stream>>>(big, vtbuf, attno);
    gemm4_kernel<MODE_F32_RES><<<dim3(1024 / 128, 8192 / 128), 256, G4_LDS_BYTES, stream>>>(
        attno, wprojT, b_proj, x, x2, nullptr, 8192, 1024, 1024, 1024, 1024);
    ln_kernel<<<8192, 256, 0, stream>>>(x2, ln2_g, ln2_b, hbuf);
    gemm8_kernel<MODE_BF16_GELU><<<dim3(4096 / 256, 8192 / 256), 512, G8_LDS_BYTES, stream>>>(
        hbuf, wfc1T, b_fc1, nullptr, big, nullptr, 8192, 4096, 1024, 1024, 1024);
    gemm4_kernel<MODE_F32_RES><<<dim3(1024 / 128, 8192 / 128), 256, G4_LDS_BYTES, stream>>>(
        big, wfc2T, b_fc2, x2, outp, nullptr, 8192, 1024, 4096, 4096, 4096);
}